// Round 1
// baseline (157.936 us; speedup 1.0000x reference)
//
#include <hip/hip_runtime.h>
#include <cstdint>
#include <cstddef>

// Problem constants
#define HW 512
#define NPIX (HW * HW)           // 262144 pixels per image
#define NIMG 16
#define NII 32                   // (input j, image n) pairs: ii = j*16 + n
#define CHUNKS 64                // blocks per ii in kernels A/C
#define CHUNK_PIX 4096
#define IN_ELEMS (NIMG * NPIX)   // 4194304 per input
#define WORDS_PER_II 4096        // 512 rows * 8 u64 words

// Workspace layout (bytes). Total ~5.3 MB.
#define WS_PARTA   0u                         // 32*64*3 doubles = 49152
#define WS_STATS   49152u                     // 32*4 doubles {mean, std, cnt, pad}
#define WS_PARTC   50176u                     // 32*64*2 int64 = 32768
#define WS_SEL     82944u                     // 32*4 ints {selMarkerFallback, selMaskFallback,-,-}
#define WS_ZMASK   83456u                     // 32 u64 (all-ones if cnt>0 else 0)
#define WS_MP      98304u                     // marker primary bitmaps: 32*4096 u64 = 1 MB
#define WS_MF      (WS_MP + 1048576u)         // marker fallback
#define WS_KP      (WS_MF + 1048576u)         // mask primary
#define WS_KF      (WS_KP + 1048576u)         // mask fallback
#define WS_ROUT    (WS_KF + 1048576u)         // reconstruction result bitmaps: 1 MB

typedef unsigned long long u64;

__device__ __forceinline__ float sigmoid_f32(float x) {
    // f64 sigmoid rounded to f32: correctly-rounded w.r.t. any reasonable f32 reference
    return (float)(1.0 / (1.0 + exp(-(double)x)));
}

// Kernel A: passthrough copy of both logit tensors into out[0..2*IN_ELEMS),
// plus per-chunk f64 partial {sum, sumsq, count} of sigmoid over nonzero pixels.
__global__ void kA_copy_reduce(const float* __restrict__ thick,
                               const float* __restrict__ thin,
                               float* __restrict__ out,
                               double* __restrict__ partA) {
    int b = blockIdx.x;          // 0..2047
    int ii = b >> 6;             // 0..31
    int chunk = b & 63;
    int j = ii >> 4, n = ii & 15;
    const float* src = (j == 0 ? thick : thin) + (size_t)n * NPIX;
    float* dst = out + (size_t)j * IN_ELEMS + (size_t)n * NPIX;
    int base = chunk * CHUNK_PIX;

    double s = 0.0, sq = 0.0, c = 0.0;
    for (int i = 0; i < 16; ++i) {
        int e = base + i * 256 + threadIdx.x;
        float x = src[e];
        dst[e] = x;
        float img = sigmoid_f32(x);
        if (img > 0.0f) {
            double d = (double)img;
            s += d; sq += d * d; c += 1.0;
        }
    }
    __shared__ double sm[256], sv[256], sc[256];
    sm[threadIdx.x] = s; sv[threadIdx.x] = sq; sc[threadIdx.x] = c;
    __syncthreads();
    for (int off = 128; off > 0; off >>= 1) {
        if (threadIdx.x < off) {
            sm[threadIdx.x] += sm[threadIdx.x + off];
            sv[threadIdx.x] += sv[threadIdx.x + off];
            sc[threadIdx.x] += sc[threadIdx.x + off];
        }
        __syncthreads();
    }
    if (threadIdx.x == 0) {
        double* p = partA + (size_t)(ii * 64 + chunk) * 3;
        p[0] = sm[0]; p[1] = sv[0]; p[2] = sc[0];
    }
}

// Kernel B: reduce 64 partials per ii -> mean, std, cnt (f64).
__global__ void kB_stats(const double* __restrict__ partA,
                         double* __restrict__ stats) {
    int ii = blockIdx.x;         // 32 blocks, 64 threads (one wave)
    int t = threadIdx.x;
    const double* p = partA + (size_t)(ii * 64 + t) * 3;
    double s = p[0], sq = p[1], c = p[2];
    for (int off = 32; off > 0; off >>= 1) {
        s  += __shfl_down(s,  (unsigned)off, 64);
        sq += __shfl_down(sq, (unsigned)off, 64);
        c  += __shfl_down(c,  (unsigned)off, 64);
    }
    if (t == 0) {
        double mean = 0.0, var = 0.0;
        if (c > 0.0) {
            mean = s / c;
            var = sq / c - mean * mean;   // == two-pass var to f64 accuracy
            if (var < 0.0) var = 0.0;
        }
        double* o = stats + (size_t)ii * 4;
        o[0] = mean; o[1] = sqrt(var); o[2] = c; o[3] = 0.0;
    }
}

// Kernel C: build 4 candidate bitmaps (marker primary/fallback, mask primary/fallback)
// via wave ballots; emit per-chunk counts of primary marker/mask bits.
__global__ void kC_bitmaps(const float* __restrict__ thick,
                           const float* __restrict__ thin,
                           const double* __restrict__ stats,
                           u64* __restrict__ mp, u64* __restrict__ mf,
                           u64* __restrict__ kp, u64* __restrict__ kf,
                           long long* __restrict__ partC) {
    int b = blockIdx.x;
    int ii = b >> 6;
    int chunk = b & 63;
    int j = ii >> 4, n = ii & 15;
    const float* src = (j == 0 ? thick : thin) + (size_t)n * NPIX;
    const double* st = stats + (size_t)ii * 4;
    double mean = st[0], sd = st[1];
    double fac = (j == 0) ? 2.0 : 4.0;
    double Tm  = mean + fac * sd;
    double Tmh = mean + (fac * 0.5) * sd;
    double Tk  = mean + 0.5 * sd;
    double Tkh = mean + 0.25 * sd;

    int t = threadIdx.x, lane = t & 63, w = t >> 6;  // 4 waves
    long long cM = 0, cK = 0;
    for (int i = 0; i < 16; ++i) {
        int e = chunk * CHUNK_PIX + i * 256 + t;
        float x = src[e];
        double img = (double)sigmoid_f32(x);
        u64 bM  = __ballot(img > Tm);
        u64 bMh = __ballot(img > Tmh);
        u64 bK  = __ballot(img > Tk);
        u64 bKh = __ballot(img > Tkh);
        if (lane == 0) {
            size_t g = (size_t)ii * WORDS_PER_II + (size_t)chunk * 64 + i * 4 + w;
            mp[g] = bM; mf[g] = bMh; kp[g] = bK; kf[g] = bKh;
            cM += (long long)__popcll(bM);
            cK += (long long)__popcll(bK);
        }
    }
    __shared__ long long aM[4], aK[4];
    if (lane == 0) { aM[w] = cM; aK[w] = cK; }
    __syncthreads();
    if (t == 0) {
        long long* p = partC + (size_t)(ii * 64 + chunk) * 2;
        p[0] = aM[0] + aM[1] + aM[2] + aM[3];
        p[1] = aK[0] + aK[1] + aK[2] + aK[3];
    }
}

// Kernel D: per-ii empty-fallback selection + cnt==0 zero-mask.
__global__ void kD_select(const long long* __restrict__ partC,
                          const double* __restrict__ stats,
                          int* __restrict__ sel,
                          u64* __restrict__ zmask) {
    int ii = threadIdx.x;
    if (ii < NII) {
        long long cM = 0, cK = 0;
        for (int c = 0; c < 64; ++c) {
            const long long* p = partC + (size_t)(ii * 64 + c) * 2;
            cM += p[0]; cK += p[1];
        }
        sel[ii * 4 + 0] = (cM == 0) ? 1 : 0;
        sel[ii * 4 + 1] = (cK == 0) ? 1 : 0;
        zmask[ii] = (stats[(size_t)ii * 4 + 2] > 0.0) ? ~0ull : 0ull;
    }
}

// Kernel E: morphological reconstruction, one block per ii.
// Whole image bitmap in LDS; synchronous Jacobi dilation R_{t+1} = dilate4(R_t) & K,
// R_0 = marker, early-exit on fixpoint, capped at 1024 iterations (= MAX_ITERS).
// LDS layout word-interleaved R[w*512 + row] -> consecutive lanes hit consecutive
// banks (2-way aliasing, free); row-major would be a 32-way bank conflict.
__global__ __launch_bounds__(512) void kE_flood(const u64* __restrict__ mp,
                                                const u64* __restrict__ mf,
                                                const u64* __restrict__ kp,
                                                const u64* __restrict__ kf,
                                                const int* __restrict__ sel,
                                                u64* __restrict__ rout) {
    int ii = blockIdx.x;
    const u64* M = (sel[ii * 4 + 0] ? mf : mp) + (size_t)ii * WORDS_PER_II;
    const u64* K = (sel[ii * 4 + 1] ? kf : kp) + (size_t)ii * WORDS_PER_II;

    __shared__ u64 R[WORDS_PER_II];
    __shared__ int changed;
    int t = threadIdx.x;  // row index 0..511

    u64 kreg[8];
    for (int w = 0; w < 8; ++w) {
        kreg[w] = K[(size_t)t * 8 + w];
        R[w * HW + t] = M[(size_t)t * 8 + w];
    }
    if (t == 0) changed = 0;
    __syncthreads();

    for (int it = 0; it < 1024; ++it) {
        u64 cur[8], up[8], dn[8];
        for (int w = 0; w < 8; ++w) {
            cur[w] = R[w * HW + t];
            up[w] = (t > 0)        ? R[w * HW + (t - 1)] : 0ull;
            dn[w] = (t < HW - 1)   ? R[w * HW + (t + 1)] : 0ull;
        }
        __syncthreads();  // all reads of old R done

        u64 diff = 0;
        for (int w = 0; w < 8; ++w) {
            u64 h = cur[w] | (cur[w] << 1) | (cur[w] >> 1)
                  | (w > 0 ? (cur[w - 1] >> 63) : 0ull)
                  | (w < 7 ? (cur[w + 1] << 63) : 0ull)
                  | up[w] | dn[w];
            u64 nw = h & kreg[w];
            diff |= nw ^ cur[w];
            R[w * HW + t] = nw;
        }
        u64 bal = __ballot(diff != 0ull);
        if ((t & 63) == 0 && bal) atomicOr(&changed, 1);
        __syncthreads();  // writes + flag sets done
        int c = changed;
        __syncthreads();  // all have read flag
        if (t == 0) changed = 0;
        if (!c) break;
    }

    for (int w = 0; w < 8; ++w)
        rout[(size_t)ii * WORDS_PER_II + (size_t)t * 8 + w] = R[w * HW + t];
}

// Kernel F: fused output = (thick_rec & zmask) | (thin_rec & zmask) as f32 0/1.
__global__ void kF_fuse(const u64* __restrict__ rout,
                        const u64* __restrict__ zmask,
                        float* __restrict__ out) {
    size_t gid = (size_t)blockIdx.x * blockDim.x + threadIdx.x;  // 1048576 threads
    size_t p = gid * 4;                                          // pixel quad
    int n = (int)(p >> 18);          // image index (NPIX = 2^18)
    int e = (int)(p & (NPIX - 1));   // pixel within image
    size_t gw = (size_t)(e >> 6);
    u64 w = (rout[(size_t)n * WORDS_PER_II + gw] & zmask[n])
          | (rout[(size_t)(16 + n) * WORDS_PER_II + gw] & zmask[16 + n]);
    int sh = e & 63;
    float4 v;
    v.x = ((w >> sh) & 1ull)       ? 1.0f : 0.0f;
    v.y = ((w >> (sh + 1)) & 1ull) ? 1.0f : 0.0f;
    v.z = ((w >> (sh + 2)) & 1ull) ? 1.0f : 0.0f;
    v.w = ((w >> (sh + 3)) & 1ull) ? 1.0f : 0.0f;
    *(float4*)(out + 2 * (size_t)IN_ELEMS + p) = v;
}

extern "C" void kernel_launch(void* const* d_in, const int* in_sizes, int n_in,
                              void* d_out, int out_size, void* d_ws, size_t ws_size,
                              hipStream_t stream) {
    const float* thick = (const float*)d_in[0];
    const float* thin  = (const float*)d_in[1];
    float* out = (float*)d_out;
    char* ws = (char*)d_ws;

    double*    partA = (double*)(ws + WS_PARTA);
    double*    stats = (double*)(ws + WS_STATS);
    long long* partC = (long long*)(ws + WS_PARTC);
    int*       sel   = (int*)(ws + WS_SEL);
    u64*       zmask = (u64*)(ws + WS_ZMASK);
    u64*       mp    = (u64*)(ws + WS_MP);
    u64*       mf    = (u64*)(ws + WS_MF);
    u64*       kp    = (u64*)(ws + WS_KP);
    u64*       kf    = (u64*)(ws + WS_KF);
    u64*       rout  = (u64*)(ws + WS_ROUT);

    kA_copy_reduce<<<NII * CHUNKS, 256, 0, stream>>>(thick, thin, out, partA);
    kB_stats<<<NII, 64, 0, stream>>>(partA, stats);
    kC_bitmaps<<<NII * CHUNKS, 256, 0, stream>>>(thick, thin, stats, mp, mf, kp, kf, partC);
    kD_select<<<1, 64, 0, stream>>>(partC, stats, sel, zmask);
    kE_flood<<<NII, 512, 0, stream>>>(mp, mf, kp, kf, sel, rout);
    kF_fuse<<<4096, 256, 0, stream>>>(rout, zmask, out);
}